// Round 9
// baseline (1053.713 us; speedup 1.0000x reference)
//
#include <hip/hip_runtime.h>
#include <cstdint>
#include <cstddef>

#define E_TOT 32768
#define HD    512
#define NR    3
#define EPAD_MAX 33152          // E_TOT + 3*128
#define NTILE_M  259            // EPAD_MAX / 128
#define NBLK     518            // NTILE_M * 2 N-tiles

typedef __attribute__((ext_vector_type(8))) short short8;
typedef __attribute__((ext_vector_type(4))) float f32x4;

static __device__ __forceinline__ unsigned short f2bf(float f) {
  union { float f; unsigned int u; } x; x.f = f;
  unsigned int u = x.u;
  return (unsigned short)((u + 0x7fffu + ((u >> 16) & 1u)) >> 16);  // RNE
}
static __device__ __forceinline__ float bf2f(unsigned short h) {
  union { unsigned int u; float f; } x; x.u = ((unsigned int)h) << 16;
  return x.f;
}

static __device__ __forceinline__ void gload_lds16(const void* g, void* l) {
  __builtin_amdgcn_global_load_lds(
      (const __attribute__((address_space(1))) unsigned int*)g,
      (__attribute__((address_space(3))) unsigned int*)l, 16, 0, 0);
}

// bijective chunked XCD swizzle (m204), NWG=518: q=64, r=6
static __device__ __forceinline__ int chunk_swz(int bid) {
  const int x = bid & 7, i = bid >> 3;
  return (x < 6) ? x * 65 + i : 390 + (x - 6) * 64 + i;
}

#define SWZ(row) (((row) >> 1) & 3)

// ---------------- prep kernels ----------------

#define AL128(x) (((x) + 127) & ~127)

__global__ void k_sort1(const int* __restrict__ roles, int* __restrict__ ctrl) {
  __shared__ int cnt[NR];
  const int t = threadIdx.x;
  if (t < NR) cnt[t] = 0;
  __syncthreads();
  int c0 = 0, c1 = 0, c2 = 0;
  for (int i = t; i < E_TOT; i += 1024) {
    const int ro = roles[i];
    c0 += (ro == 0); c1 += (ro == 1); c2 += (ro == 2);
  }
  if (c0) atomicAdd(&cnt[0], c0);
  if (c1) atomicAdd(&cnt[1], c1);
  if (c2) atomicAdd(&cnt[2], c2);
  __syncthreads();
  if (t == 0) {
    const int off1 = AL128(cnt[0]);
    const int off2 = AL128(off1 + cnt[1]);
    const int ptot = AL128(off2 + cnt[2]);
    ctrl[0] = cnt[0]; ctrl[1] = cnt[1]; ctrl[2] = cnt[2];
    ctrl[4] = 0; ctrl[5] = off1; ctrl[6] = off2; ctrl[7] = ptot;
    ctrl[9] = 0; ctrl[10] = off1; ctrl[11] = off2;
  }
}

__global__ void k_scatter(const int* __restrict__ roles, int* __restrict__ ctrl,
                          int* __restrict__ perm) {
  int e = blockIdx.x * 256 + threadIdx.x;
  int lane = threadIdx.x & 63;
  int role = roles[e];
#pragma unroll
  for (int r = 0; r < NR; ++r) {
    unsigned long long m = __ballot(role == r);
    if (!m) continue;
    int leader = __ffsll((unsigned long long)m) - 1;
    int base = 0;
    if (lane == leader) base = atomicAdd(&ctrl[9 + r], (int)__popcll(m));
    base = __shfl(base, leader);
    if (role == r) {
      int rank = (int)__popcll(m & ((1ull << lane) - 1ull));
      perm[base + rank] = e;
    }
  }
}

// fill pad slots through EPAD_MAX so gather reads valid perm everywhere
__global__ void k_padfill(const int* __restrict__ ctrl, int* __restrict__ perm) {
#pragma unroll
  for (int r = 0; r < NR; ++r) {
    const int start = ctrl[4 + r] + ctrl[r];
    const int end = (r < 2) ? ctrl[5 + r] : EPAD_MAX;
    const int fill = (ctrl[r] > 0) ? perm[ctrl[4 + r]] : 0;
    for (int i = start + (int)threadIdx.x; i < end; i += 256) perm[i] = fill;
  }
}

__global__ void k_convw(const float* __restrict__ W, const float* __restrict__ U,
                        const float* __restrict__ P1, const float* __restrict__ P2,
                        const int* __restrict__ dlayer, short* __restrict__ dst) {
  const int per = NR * HD * HD;
  const int which = blockIdx.y;
  const float* src = (which == 0) ? W : (which == 1) ? U : (which == 2) ? P1 : P2;
  src += (size_t)dlayer[0] * per;
  short* d = dst + (size_t)which * per;
  int i = (blockIdx.x * 256 + threadIdx.x) * 4;
  if (i >= per) return;
  float4 v = *(const float4*)(src + i);
  short4 o;
  o.x = (short)f2bf(v.x); o.y = (short)f2bf(v.y);
  o.z = (short)f2bf(v.z); o.w = (short)f2bf(v.w);
  *(short4*)(d + i) = o;
}

// gather-by-perm + convert to bf16, sorted+padded rows (64 threads/row)
__global__ void k_gather(const float* __restrict__ v, const float* __restrict__ r,
                         const int* __restrict__ perm,
                         short* __restrict__ vbf, short* __restrict__ rbf) {
  const int idx = blockIdx.x * 256 + threadIdx.x;   // EPAD_MAX*64 threads
  const int row = idx >> 6;
  const int kc = (idx & 63) << 3;
  const int g = perm[row];
  const float4* pv = (const float4*)(v + (size_t)g * HD + kc);
  const float4* pr = (const float4*)(r + (size_t)g * HD + kc);
  const float4 a0 = pv[0], a1 = pv[1];
  const float4 b0 = pr[0], b1 = pr[1];
  short8 sa, sb;
#pragma unroll
  for (int j = 0; j < 4; ++j) {
    sa[j] = (short)f2bf(((const float*)&a0)[j]);
    sa[4 + j] = (short)f2bf(((const float*)&a1)[j]);
    sb[j] = (short)f2bf(((const float*)&b0)[j]);
    sb[4 + j] = (short)f2bf(((const float*)&b1)[j]);
  }
  *(short8*)(vbf + (size_t)row * HD + kc) = sa;
  *(short8*)(rbf + (size_t)row * HD + kc) = sb;
}

// ---------------- pipelined GEMM ----------------
// BM=128, BN=256, BK=32. 512 thr = 8 waves (2M x 4N), wave tile 64x64.
// acc = 4x4 f32x4 = 64 floats/lane (NO-SPILL budget, R8 lesson).
// LDS 48KB dbuf: slot = [A 0..511 | B 512..1535] short8 units; 3 blocks/CU.
// XOR swizzle u' = u ^ ((row>>1)&3), both-sides (0-conflict, R5-verified).
// 2 phases/K-tile, counted vmcnt(2) (T4), setprio around MFMA (T5).
// D-frag: col=lane&15, row=(lane>>4)*4+reg [m89/m91-verified].
//
// MODE 0: outS = A0@B^T + bias           (bf16, sorted rows)
// MODE 1: outS = relu((A0*A1)@B^T + bias) (product reg-staged in A-path, T14)
// MODE 2: outF[perm[row]] = A0@B^T + bias (f32 scatter)
template <int MODE>
__global__ __launch_bounds__(512, 6) void k_mm(
    const short* __restrict__ A0, const short* __restrict__ A1,
    const short* __restrict__ Ball, const float* __restrict__ biasAll,
    const int* __restrict__ dlayer, const int* __restrict__ ctrl,
    const int* __restrict__ perm, short* __restrict__ outS,
    float* __restrict__ outF) {
  __shared__ short8 L[2][1536];

  const int lb = chunk_swz(blockIdx.x);
  const int m0 = (lb >> 1) * 128, n0 = (lb & 1) * 256;
  if (m0 >= ctrl[7]) return;
  const int role = (m0 >= ctrl[6]) ? 2 : (m0 >= ctrl[5] ? 1 : 0);

  const int tid = threadIdx.x, lane = tid & 63, wv = tid >> 6;
  const int wr = wv >> 2, wc = wv & 3, krow = lane & 15, ku = lane >> 4;

  const short* Bp = Ball + (size_t)role * HD * HD;

  // staging descriptors (pre-swizzled sources, linear LDS dests)
  const int arow = tid >> 2, au = tid & 3;
  const size_t aoff = (size_t)(m0 + arow) * HD + (au ^ SWZ(arow)) * 8;
  size_t boff[2];
#pragma unroll
  for (int j = 0; j < 2; ++j) {
    const int br = j * 128 + arow;
    boff[j] = (size_t)(n0 + br) * HD + (au ^ SWZ(br)) * 8;
  }

  f32x4 acc[4][4];
#pragma unroll
  for (int a = 0; a < 4; ++a)
#pragma unroll
    for (int b = 0; b < 4; ++b) acc[a][b] = (f32x4)0.f;
  short8 fa[4], fb[4];
  short8 av, ar;

#define ISSA(bi, K0)                                                           \
  if constexpr (MODE == 1) {                                                   \
    av = *(const short8*)(A0 + aoff + (K0));                                   \
    ar = *(const short8*)(A1 + aoff + (K0));                                   \
  } else {                                                                     \
    gload_lds16(A0 + aoff + (K0), &L[bi][tid]);                                \
  }

#define ISSB(bi, K0)                                                           \
  _Pragma("unroll") for (int j = 0; j < 2; ++j)                                \
    gload_lds16(Bp + boff[j] + (K0), &L[bi][512 + j * 512 + tid]);

#define AWR(bi)                                                                \
  {                                                                            \
    short8 o;                                                                  \
    _Pragma("unroll") for (int j = 0; j < 8; ++j)                              \
      o[j] = (short)f2bf(bf2f((unsigned short)av[j]) *                         \
                         bf2f((unsigned short)ar[j]));                         \
    L[bi][tid] = o;                                                            \
  }

#define RDA(mi, bi)                                                            \
  { const int r_ = wr * 64 + (mi) * 16 + krow;                                 \
    fa[mi] = L[bi][r_ * 4 + (ku ^ SWZ(r_))]; }

#define RDB(ni, bi)                                                            \
  { const int r_ = wc * 64 + (ni) * 16 + krow;                                 \
    fb[ni] = L[bi][512 + r_ * 4 + (ku ^ SWZ(r_))]; }

#define TAIL(MI0)                                                              \
  __builtin_amdgcn_s_barrier();                                                \
  asm volatile("s_waitcnt lgkmcnt(0)" ::: "memory");                           \
  __builtin_amdgcn_sched_barrier(0);                                           \
  __builtin_amdgcn_s_setprio(1);                                               \
  _Pragma("unroll") for (int mi = 0; mi < 2; ++mi)                             \
    _Pragma("unroll") for (int ni = 0; ni < 4; ++ni)                           \
      acc[(MI0) + mi][ni] = __builtin_amdgcn_mfma_f32_16x16x32_bf16(           \
          fa[(MI0) + mi], fb[ni], acc[(MI0) + mi][ni], 0, 0, 0);               \
  __builtin_amdgcn_s_setprio(0);                                               \
  __builtin_amdgcn_s_barrier();

  // ---- prologue: A(0)+B(0) -> slot0, B(1) -> slot1 ----
  ISSA(0, 0)
  ISSB(0, 0)
  ISSB(1, 32)
  asm volatile("s_waitcnt vmcnt(2)" ::: "memory");   // A(0),B(0) done; B(1) in flight
  if constexpr (MODE == 1) {
    AWR(0)
    asm volatile("s_waitcnt lgkmcnt(0)" ::: "memory");
  }
  __builtin_amdgcn_s_barrier();

  int cur = 0;
  for (int t = 0; t < 16; ++t) {
    const int nxt = cur ^ 1;

    // P0: B-frags + A-lo frags; issue A(t+1) -> nxt
    RDB(0, cur) RDB(1, cur) RDB(2, cur) RDB(3, cur)
    RDA(0, cur) RDA(1, cur)
    if (t < 15) { ISSA(nxt, (t + 1) * 32) }
    TAIL(0)

    // P1: A-hi frags; issue B(t+2) -> cur's B (dead after P0); counted gate
    RDA(2, cur) RDA(3, cur)
    if (t < 14) {
      ISSB(cur, (t + 2) * 32)
      asm volatile("s_waitcnt vmcnt(2)" ::: "memory");  // A(t+1)/B(t+1) done
    } else {
      asm volatile("s_waitcnt vmcnt(0)" ::: "memory");
    }
    if constexpr (MODE == 1) {
      if (t < 15) { AWR(nxt) }
    }
    TAIL(2)

    cur = nxt;
  }

  // ---- epilogue ----
  const int ld = dlayer[0];
  const float* bias = biasAll + ((size_t)ld * NR + role) * HD + n0;

  int pg[4][4];
  if constexpr (MODE == 2) {
#pragma unroll
    for (int mi = 0; mi < 4; ++mi)
#pragma unroll
      for (int j = 0; j < 4; ++j)
        pg[mi][j] = perm[m0 + wr * 64 + mi * 16 + ku * 4 + j];
  }

#pragma unroll
  for (int ni = 0; ni < 4; ++ni) {
    const int col = wc * 64 + ni * 16 + krow;
    const float b = bias[col];
#pragma unroll
    for (int mi = 0; mi < 4; ++mi) {
      const int rbase = m0 + wr * 64 + mi * 16 + ku * 4;
#pragma unroll
      for (int j = 0; j < 4; ++j) {
        float val = acc[mi][ni][j] + b;
        if constexpr (MODE == 0) {
          outS[(size_t)(rbase + j) * HD + n0 + col] = (short)f2bf(val);
        } else if constexpr (MODE == 1) {
          val = fmaxf(val, 0.f);
          outS[(size_t)(rbase + j) * HD + n0 + col] = (short)f2bf(val);
        } else {
          outF[(size_t)pg[mi][j] * HD + n0 + col] = val;
        }
      }
    }
  }
#undef ISSA
#undef ISSB
#undef AWR
#undef RDA
#undef RDB
#undef TAIL
}

// ---------------- launch ----------------

extern "C" void kernel_launch(void* const* d_in, const int* in_sizes, int n_in,
                              void* d_out, int out_size, void* d_ws, size_t ws_size,
                              hipStream_t stream) {
  const float* v    = (const float*)d_in[0];
  const float* r    = (const float*)d_in[1];
  const int*   rol  = (const int*)d_in[2];
  const float* W    = (const float*)d_in[3];
  const float* Wb   = (const float*)d_in[4];
  const float* U    = (const float*)d_in[5];
  const float* Ub   = (const float*)d_in[6];
  const float* P1   = (const float*)d_in[7];
  const float* P1b  = (const float*)d_in[8];
  const float* P2   = (const float*)d_in[9];
  const float* P2b  = (const float*)d_in[10];
  const int*   dly  = (const int*)d_in[11];

  char* ws = (char*)d_ws;
  int* ctrl = (int*)ws;                          // 256 B
  int* perm = (int*)(ws + 256);                  // EPAD_MAX ints -> ends 132,864
  short* Wbf = (short*)(ws + 132864);            // 4 x NR*HD*HD bf16
  short* Ubf  = Wbf + (size_t)NR * HD * HD;
  short* P1bf = Ubf + (size_t)NR * HD * HD;
  short* P2bf = P1bf + (size_t)NR * HD * HD;     // ends 6,424,320
  short* vbf = (short*)(ws + 6424320);           // EPAD_MAX*HD bf16 -> ends 40,371,968
  short* rbf = vbf + (size_t)EPAD_MAX * HD;      // ends 74,319,616 (< R5-proven 75.1MB)
  short* vp = (short*)d_out;                     // d_out front (dead before final scatter)
  short* rp = vbf;                               // over vbf (dead after S1a)
  short* tb = rbf;                               // over rbf (dead after S1b)
  float* out = (float*)d_out;

  k_sort1<<<1, 1024, 0, stream>>>(rol, ctrl);
  k_scatter<<<E_TOT / 256, 256, 0, stream>>>(rol, ctrl, perm);
  k_padfill<<<1, 256, 0, stream>>>(ctrl, perm);
  k_convw<<<dim3((NR * HD * HD) / 4 / 256, 4, 1), 256, 0, stream>>>(W, U, P1, P2, dly, Wbf);
  k_gather<<<EPAD_MAX * 64 / 256, 256, 0, stream>>>(v, r, perm, vbf, rbf);

  // S1a: vp = vbf@W^T + wb     (vp -> d_out front)
  k_mm<0><<<NBLK, 512, 0, stream>>>(vbf, nullptr, Wbf, Wb, dly, ctrl, perm, vp, nullptr);
  // S1b: rp = rbf@U^T + ub     (rp -> over vbf, dead now)
  k_mm<0><<<NBLK, 512, 0, stream>>>(rbf, nullptr, Ubf, Ub, dly, ctrl, perm, rp, nullptr);
  // S2: tb = relu((vp*rp)@P1^T + b1)   (tb -> over rbf, dead now)
  k_mm<1><<<NBLK, 512, 0, stream>>>(vp, rp, P1bf, P1b, dly, ctrl, perm, tb, nullptr);
  // S3: out[perm] = tb@P2^T + b2       (overwrites all of d_out)
  k_mm<2><<<NBLK, 512, 0, stream>>>(tb, nullptr, P2bf, P2b, dly, ctrl, perm, nullptr, out);

  (void)in_sizes; (void)n_in; (void)out_size; (void)ws_size;
}

// Round 10
// 244.599 us; speedup vs baseline: 4.3079x; 4.3079x over previous
//
#include <hip/hip_runtime.h>
#include <cstdint>
#include <cstddef>

#define E_TOT 32768
#define HD    512
#define NR    3
#define EPAD_MAX 33536          // E_TOT + 3*256, 131 M-tiles of 256
#define NBLK  262               // 131 * 2 N-tiles
#define NBLK2 524               // paired S1

typedef __attribute__((ext_vector_type(8))) short short8;
typedef __attribute__((ext_vector_type(4))) float f32x4;

static __device__ __forceinline__ unsigned short f2bf(float f) {
  union { float f; unsigned int u; } x; x.f = f;
  unsigned int u = x.u;
  return (unsigned short)((u + 0x7fffu + ((u >> 16) & 1u)) >> 16);  // RNE
}
static __device__ __forceinline__ float bf2f(unsigned short h) {
  union { unsigned int u; float f; } x; x.u = ((unsigned int)h) << 16;
  return x.f;
}

static __device__ __forceinline__ void gload_lds16(const void* g, void* l) {
  __builtin_amdgcn_global_load_lds(
      (const __attribute__((address_space(1))) unsigned int*)g,
      (__attribute__((address_space(3))) unsigned int*)l, 16, 0, 0);
}

// bijective chunked XCD swizzle (m204)
template <int NWG>
static __device__ __forceinline__ int chunk_swz(int bid) {
  constexpr int q = NWG / 8, r = NWG % 8;
  const int x = bid & 7, i = bid >> 3;
  return (x < r) ? x * (q + 1) + i : r * (q + 1) + (x - r) * q + i;
}

// ---------------- prep kernels ----------------

#define AL256(x) (((x) + 255) & ~255)

__global__ void k_sort1(const int* __restrict__ roles, int* __restrict__ ctrl) {
  __shared__ int cnt[NR];
  const int t = threadIdx.x;
  if (t < NR) cnt[t] = 0;
  __syncthreads();
  int c0 = 0, c1 = 0, c2 = 0;
  for (int i = t; i < E_TOT; i += 1024) {
    const int ro = roles[i];
    c0 += (ro == 0); c1 += (ro == 1); c2 += (ro == 2);
  }
  if (c0) atomicAdd(&cnt[0], c0);
  if (c1) atomicAdd(&cnt[1], c1);
  if (c2) atomicAdd(&cnt[2], c2);
  __syncthreads();
  if (t == 0) {
    const int off1 = AL256(cnt[0]);
    const int off2 = AL256(off1 + cnt[1]);
    const int ptot = AL256(off2 + cnt[2]);
    ctrl[0] = cnt[0]; ctrl[1] = cnt[1]; ctrl[2] = cnt[2];
    ctrl[4] = 0; ctrl[5] = off1; ctrl[6] = off2; ctrl[7] = ptot;
    ctrl[9] = 0; ctrl[10] = off1; ctrl[11] = off2;
  }
}

__global__ void k_scatter(const int* __restrict__ roles, int* __restrict__ ctrl,
                          int* __restrict__ perm) {
  int e = blockIdx.x * 256 + threadIdx.x;
  int lane = threadIdx.x & 63;
  int role = roles[e];
#pragma unroll
  for (int r = 0; r < NR; ++r) {
    unsigned long long m = __ballot(role == r);
    if (!m) continue;
    int leader = __ffsll((unsigned long long)m) - 1;
    int base = 0;
    if (lane == leader) base = atomicAdd(&ctrl[9 + r], (int)__popcll(m));
    base = __shfl(base, leader);
    if (role == r) {
      int rank = (int)__popcll(m & ((1ull << lane) - 1ull));
      perm[base + rank] = e;
    }
  }
}

// fill pad slots through EPAD_MAX so k_gather reads valid perm everywhere
__global__ void k_padfill(const int* __restrict__ ctrl, int* __restrict__ perm) {
#pragma unroll
  for (int r = 0; r < NR; ++r) {
    const int start = ctrl[4 + r] + ctrl[r];
    const int end = (r < 2) ? ctrl[5 + r] : EPAD_MAX;
    const int fill = (ctrl[r] > 0) ? perm[ctrl[4 + r]] : 0;
    for (int i = start + (int)threadIdx.x; i < end; i += 256) perm[i] = fill;
  }
}

__global__ void k_convw(const float* __restrict__ W, const float* __restrict__ U,
                        const float* __restrict__ P1, const float* __restrict__ P2,
                        const int* __restrict__ dlayer, short* __restrict__ dst) {
  const int per = NR * HD * HD;
  const int which = blockIdx.y;
  const float* src = (which == 0) ? W : (which == 1) ? U : (which == 2) ? P1 : P2;
  src += (size_t)dlayer[0] * per;
  short* d = dst + (size_t)which * per;
  int i = (blockIdx.x * 256 + threadIdx.x) * 4;
  if (i >= per) return;
  float4 v = *(const float4*)(src + i);
  short4 o;
  o.x = (short)f2bf(v.x); o.y = (short)f2bf(v.y);
  o.z = (short)f2bf(v.z); o.w = (short)f2bf(v.w);
  *(short4*)(d + i) = o;
}

// gather-by-perm + convert to bf16, sorted+padded rows (64 threads/row)
__global__ void k_gather(const float* __restrict__ v, const float* __restrict__ r,
                         const int* __restrict__ perm,
                         short* __restrict__ vbf, short* __restrict__ rbf) {
  const int idx = blockIdx.x * 256 + threadIdx.x;   // EPAD_MAX*64 threads
  const int row = idx >> 6;
  const int kc = (idx & 63) << 3;
  const int g = perm[row];
  const float4* pv = (const float4*)(v + (size_t)g * HD + kc);
  const float4* pr = (const float4*)(r + (size_t)g * HD + kc);
  const float4 a0 = pv[0], a1 = pv[1];
  const float4 b0 = pr[0], b1 = pr[1];
  short8 sa, sb;
#pragma unroll
  for (int j = 0; j < 4; ++j) {
    sa[j] = (short)f2bf(((const float*)&a0)[j]);
    sa[4 + j] = (short)f2bf(((const float*)&a1)[j]);
    sb[j] = (short)f2bf(((const float*)&b0)[j]);
    sb[4 + j] = (short)f2bf(((const float*)&b1)[j]);
  }
  *(short8*)(vbf + (size_t)row * HD + kc) = sa;
  *(short8*)(rbf + (size_t)row * HD + kc) = sb;
}

// ---------------- 4-phase pipelined GEMM (R7-verified structure) ----------------
// BM=BN=256, BK=64, 512 thr = 8 waves (2M x 4N), wave tile 128x64.
// LDS 128KB: [slot 0/1][A 2048 units | B 2048 units], unit = short8 (16B).
// Unit layout: half*1024 + (row&127)*8 + (u ^ (row&7))  [XOR swizzle].
// Per K-tile t (slot cur): P0 B-frags+A-q0, issue A(t+1)->nxt; P1/P2 A-q1/q2,
// stage B(t+2) halves into cur (B dead after P0); P3 A-q3, write A(t+1),
// vmcnt(4) -- never 0 mid-loop. launch_bounds(512,2): VGPR cap 256,
// measured 128 no-spill (R7). D-frag: col=lane&15, row=(lane>>4)*4+reg.
//
// AM 0: A = bf16 rows via global_load_lds. AM 1: A = vp*rp product, reg-staged.
// OM 0: bf16 out + bias. OM 1: bf16 out + bias + relu. OM 2: f32 perm-scatter.
// PAIRED: grid doubled; pair bit selects {A0,B0,bias0,outS0} vs {A1,B1,bias1,outS1}.
template <int AM, int OM, int PAIRED>
__global__ __launch_bounds__(512, 2) void k_gemm(
    const short* __restrict__ A0, const short* __restrict__ A1,
    const short* __restrict__ B0, const short* __restrict__ B1,
    const float* __restrict__ bias0, const float* __restrict__ bias1,
    const int* __restrict__ dlayer, const int* __restrict__ ctrl,
    const int* __restrict__ perm, short* __restrict__ outS0,
    short* __restrict__ outS1, float* __restrict__ outF) {
  __shared__ short8 lds8[2][4096];   // 128 KB

  int lb = chunk_swz<PAIRED ? NBLK2 : NBLK>(blockIdx.x);
  int pair = 0;
  if constexpr (PAIRED) { pair = lb >= NBLK ? 1 : 0; lb -= pair * NBLK; }
  const int m0 = (lb >> 1) * 256, n0 = (lb & 1) * 256;
  if (m0 >= ctrl[7]) return;
  const int role = (m0 >= ctrl[6]) ? 2 : (m0 >= ctrl[5] ? 1 : 0);

  const int tid = threadIdx.x;
  const int lane = tid & 63;
  const int wv = tid >> 6;
  const int wr = wv >> 2, wc = wv & 3;
  const int krow = lane & 15, ku = lane >> 4;

  const short* Brole = (PAIRED && pair ? B1 : B0) + (size_t)role * HD * HD;
  const short* Ap = (PAIRED && pair) ? A1 : A0;

  // B stage source offsets (elements, without k0); g = j*512+tid
  unsigned bsrc[4];
#pragma unroll
  for (int j = 0; j < 4; ++j) {
    const int g = j * 512 + tid;
    const int u = (g & 7) ^ ((g >> 3) & 7);
    bsrc[j] = (unsigned)(n0 + (g >> 3)) * HD + u * 8;
  }
  // A stage descriptors
  unsigned asrc[4];                    // AM0 gload
  unsigned aoff[4];                    // AM1 reg-stage row offsets
  if constexpr (AM == 0) {
#pragma unroll
    for (int j = 0; j < 4; ++j) {
      const int g = j * 512 + tid;
      const int u = (g & 7) ^ ((g >> 3) & 7);
      asrc[j] = (unsigned)(m0 + (g >> 3)) * HD + u * 8;
    }
  } else {
    const int uA = ((tid & 7) ^ ((tid >> 3) & 7)) * 8;
#pragma unroll
    for (int i = 0; i < 4; ++i)
      aoff[i] = (unsigned)(m0 + (tid >> 3) + i * 64) * HD + uA;
  }

  // fragment LDS indices
  int kx[2];
#pragma unroll
  for (int ks = 0; ks < 2; ++ks) kx[ks] = (ks * 4 + ku) ^ (krow & 7);
  const int gA = wr * 1024 + krow * 8;
  const int gB = 2048 + (wc >> 1) * 1024 + ((wc & 1) * 64 + krow) * 8;

  f32x4 acc[8][4];
#pragma unroll
  for (int a = 0; a < 8; ++a)
#pragma unroll
    for (int b = 0; b < 4; ++b) acc[a][b] = (f32x4)0.f;

  short8 av[4], ar[4];
  short8 fa[2][2], fb[4][2];

#define ISSUE_A(K0)                                                            \
  if constexpr (AM == 1) {                                                     \
    _Pragma("unroll") for (int i = 0; i < 4; ++i) {                            \
      av[i] = *(const short8*)(A0 + (size_t)aoff[i] + (K0));                   \
      ar[i] = *(const short8*)(A1 + (size_t)aoff[i] + (K0));                   \
    }                                                                          \
  } else {                                                                     \
    _Pragma("unroll") for (int j = 0; j < 4; ++j)                              \
      gload_lds16(Ap + (size_t)asrc[j] + (K0), Ln + j * 512 + tid);            \
  }

#define WRITE_A()                                                              \
  if constexpr (AM == 1) {                                                     \
    _Pragma("unroll") for (int i = 0; i < 4; ++i) {                            \
      short8 o;                                                                \
      _Pragma("unroll") for (int j = 0; j < 8; ++j)                            \
        o[j] = (short)f2bf(bf2f((unsigned short)av[i][j]) *                    \
                           bf2f((unsigned short)ar[i][j]));                    \
      Ln[i * 512 + tid] = o;                                                   \
    }                                                                          \
  }

#define STAGE_B(JB, K0)                                                        \
  _Pragma("unroll") for (int j = JB; j < (JB) + 2; ++j)                        \
    gload_lds16(Brole + (size_t)bsrc[j] + (K0), Lc + 2048 + j * 512 + tid);

#define READ_FA(MI0)                                                           \
  _Pragma("unroll") for (int mi = 0; mi < 2; ++mi)                             \
    _Pragma("unroll") for (int ks = 0; ks < 2; ++ks)                           \
      fa[mi][ks] = Lc[gA + ((MI0) + mi) * 128 + kx[ks]];

#define PHASE_TAIL(MI0)                                                        \
  __builtin_amdgcn_s_barrier();                                                \
  asm volatile("s_waitcnt lgkmcnt(0)" ::: "memory");                           \
  __builtin_amdgcn_sched_barrier(0);                                           \
  __builtin_amdgcn_s_setprio(1);                                               \
  _Pragma("unroll") for (int ks = 0; ks < 2; ++ks)                             \
    _Pragma("unroll") for (int mi = 0; mi < 2; ++mi)                           \
      _Pragma("unroll") for (int ni = 0; ni < 4; ++ni)                         \
        acc[(MI0) + mi][ni] = __builtin_amdgcn_mfma_f32_16x16x32_bf16(         \
            fa[mi][ks], fb[ni][ks], acc[(MI0) + mi][ni], 0, 0, 0);             \
  __builtin_amdgcn_s_setprio(0);                                               \
  __builtin_amdgcn_s_barrier();

  // ---- prologue: A(0), B(0) -> slot0, B(1) -> slot1 ----
  {
    short8* Ln = &lds8[0][0];
    short8* Lc = &lds8[0][0];
    ISSUE_A(0)
    STAGE_B(0, 0) STAGE_B(2, 0)
    Lc = &lds8[1][0];
    STAGE_B(0, 64) STAGE_B(2, 64)
    asm volatile("s_waitcnt vmcnt(4)" ::: "memory");
    WRITE_A()
    asm volatile("s_waitcnt lgkmcnt(0)" ::: "memory");
    __builtin_amdgcn_s_barrier();
  }

  int cur = 0;
  for (int t = 0; t < 8; ++t) {
    short8* Lc = &lds8[cur][0];
    short8* Ln = &lds8[cur ^ 1][0];
    const int k0a = (t + 1) * 64;
    const int k0b = (t + 2) * 64;

    // P0: B-frags + A q0; issue next A
#pragma unroll
    for (int ni = 0; ni < 4; ++ni)
#pragma unroll
      for (int ks = 0; ks < 2; ++ks)
        fb[ni][ks] = Lc[gB + ni * 128 + kx[ks]];
    READ_FA(0)
    if (t < 7) { ISSUE_A(k0a) }
    PHASE_TAIL(0)

    // P1: A q1; stage B_lo(t+2) into cur
    READ_FA(2)
    if (t < 6) { STAGE_B(0, k0b) }
    PHASE_TAIL(2)

    // P2: A q2; stage B_hi(t+2) into cur
    READ_FA(4)
    if (t < 6) { STAGE_B(2, k0b) }
    PHASE_TAIL(4)

    // P3: A q3; write A(t+1) -> cur^1; counted vmcnt
    READ_FA(6)
    if (t < 7) { WRITE_A() }
    if (t < 6) asm volatile("s_waitcnt vmcnt(4)" ::: "memory");
    else       asm volatile("s_waitcnt vmcnt(0)" ::: "memory");
    PHASE_TAIL(6)

    cur ^= 1;
  }

  // ---- epilogue ----
  const int ld = dlayer[0];
  const float* bias = (PAIRED && pair ? bias1 : bias0) +
                      ((size_t)ld * NR + role) * HD + n0;
  short* outS = (PAIRED && pair) ? outS1 : outS0;

  int pg[8][4];
  if constexpr (OM == 2) {
#pragma unroll
    for (int mi = 0; mi < 8; ++mi)
#pragma unroll
      for (int j = 0; j < 4; ++j)
        pg[mi][j] = perm[m0 + wr * 128 + mi * 16 + ku * 4 + j];
  }

#pragma unroll
  for (int ni = 0; ni < 4; ++ni) {
    const int col = wc * 64 + ni * 16 + krow;
    const float b = bias[col];
#pragma unroll
    for (int mi = 0; mi < 8; ++mi) {
      const int rbase = m0 + wr * 128 + mi * 16 + ku * 4;
#pragma unroll
      for (int j = 0; j < 4; ++j) {
        float val = acc[mi][ni][j] + b;
        if constexpr (OM == 0) {
          outS[(size_t)(rbase + j) * HD + n0 + col] = (short)f2bf(val);
        } else if constexpr (OM == 1) {
          val = fmaxf(val, 0.f);
          outS[(size_t)(rbase + j) * HD + n0 + col] = (short)f2bf(val);
        } else {
          outF[(size_t)pg[mi][j] * HD + n0 + col] = val;
        }
      }
    }
  }
#undef ISSUE_A
#undef WRITE_A
#undef STAGE_B
#undef READ_FA
#undef PHASE_TAIL
}

// ---------------- launch ----------------

extern "C" void kernel_launch(void* const* d_in, const int* in_sizes, int n_in,
                              void* d_out, int out_size, void* d_ws, size_t ws_size,
                              hipStream_t stream) {
  const float* v    = (const float*)d_in[0];
  const float* r    = (const float*)d_in[1];
  const int*   rol  = (const int*)d_in[2];
  const float* W    = (const float*)d_in[3];
  const float* Wb   = (const float*)d_in[4];
  const float* U    = (const float*)d_in[5];
  const float* Ub   = (const float*)d_in[6];
  const float* P1   = (const float*)d_in[7];
  const float* P1b  = (const float*)d_in[8];
  const float* P2   = (const float*)d_in[9];
  const float* P2b  = (const float*)d_in[10];
  const int*   dly  = (const int*)d_in[11];

  char* ws = (char*)d_ws;
  int* ctrl = (int*)ws;                          // 256 B
  int* perm = (int*)(ws + 256);                  // EPAD_MAX ints -> ends 134,400
  short* Wbf = (short*)(ws + 134400);            // 4 x NR*HD*HD bf16
  short* Ubf  = Wbf + (size_t)NR * HD * HD;
  short* P1bf = Ubf + (size_t)NR * HD * HD;
  short* P2bf = P1bf + (size_t)NR * HD * HD;     // ends 6,425,856
  short* vbf = (short*)(ws + 6425856);           // EPAD_MAX*HD bf16 -> ends 40,766,720
  short* rbf = vbf + (size_t)EPAD_MAX * HD;      // ends 75,107,584 (proven bound R5/R7)
  short* vp  = (short*)d_out;                    // d_out front 34.3MB (dead before S3)
  float* out = (float*)d_out;

  const bool bigws = ws_size >= 109448448ull;    // rp extension fits?
  short* rp = bigws ? (short*)(ws + 75107584) : vbf;  // paired: ws ext; seq: over vbf
  short* tb = rbf;                               // over rbf (dead after S1 reads it)

  k_sort1<<<1, 1024, 0, stream>>>(rol, ctrl);
  k_scatter<<<E_TOT / 256, 256, 0, stream>>>(rol, ctrl, perm);
  k_padfill<<<1, 256, 0, stream>>>(ctrl, perm);
  k_convw<<<dim3((NR * HD * HD) / 4 / 256, 4, 1), 256, 0, stream>>>(W, U, P1, P2, dly, Wbf);
  k_gather<<<EPAD_MAX * 64 / 256, 256, 0, stream>>>(v, r, perm, vbf, rbf);

  if (bigws) {
    // S1 paired: vp = vbf@W^T+wb, rp = rbf@U^T+ub  (one 524-block dispatch)
    k_gemm<0, 0, 1><<<NBLK2, 512, 0, stream>>>(vbf, rbf, Wbf, Ubf, Wb, Ub,
                                               dly, ctrl, perm, vp, rp, nullptr);
  } else {
    k_gemm<0, 0, 0><<<NBLK, 512, 0, stream>>>(vbf, nullptr, Wbf, nullptr, Wb, nullptr,
                                              dly, ctrl, perm, vp, nullptr, nullptr);
    // rp -> over vbf (vbf dead after the S1a dispatch completes; stream-ordered)
    k_gemm<0, 0, 0><<<NBLK, 512, 0, stream>>>(rbf, nullptr, Ubf, nullptr, Ub, nullptr,
                                              dly, ctrl, perm, rp, nullptr, nullptr);
  }
  // S2: tb = relu((vp*rp)@P1^T + b1)  (product reg-staged; tb -> over rbf)
  k_gemm<1, 1, 0><<<NBLK, 512, 0, stream>>>(vp, rp, P1bf, nullptr, P1b, nullptr,
                                            dly, ctrl, perm, tb, nullptr, nullptr);
  // S3: out[perm] = tb@P2^T + b2      (overwrites all of d_out)
  k_gemm<0, 2, 0><<<NBLK, 512, 0, stream>>>(tb, nullptr, P2bf, nullptr, P2b, nullptr,
                                            dly, ctrl, perm, nullptr, nullptr, out);

  (void)in_sizes; (void)n_in; (void)out_size;
}

// Round 11
// 242.205 us; speedup vs baseline: 4.3505x; 1.0099x over previous
//
#include <hip/hip_runtime.h>
#include <cstdint>
#include <cstddef>

#define E_TOT 32768
#define HD    512
#define NR    3
#define EPAD_MAX 33536          // E_TOT + 3*256, 131 M-tiles of 256
#define NBLK  262               // 131 * 2 N-tiles
#define NBLK2 524               // paired S1

typedef __attribute__((ext_vector_type(8))) short short8;
typedef __attribute__((ext_vector_type(4))) float f32x4;

static __device__ __forceinline__ unsigned short f2bf(float f) {
  union { float f; unsigned int u; } x; x.f = f;
  unsigned int u = x.u;
  return (unsigned short)((u + 0x7fffu + ((u >> 16) & 1u)) >> 16);  // RNE
}
static __device__ __forceinline__ float bf2f(unsigned short h) {
  union { unsigned int u; float f; } x; x.u = ((unsigned int)h) << 16;
  return x.f;
}

static __device__ __forceinline__ void gload_lds16(const void* g, void* l) {
  __builtin_amdgcn_global_load_lds(
      (const __attribute__((address_space(1))) unsigned int*)g,
      (__attribute__((address_space(3))) unsigned int*)l, 16, 0, 0);
}

// bijective chunked XCD swizzle (m204)
template <int NWG>
static __device__ __forceinline__ int chunk_swz(int bid) {
  constexpr int q = NWG / 8, r = NWG % 8;
  const int x = bid & 7, i = bid >> 3;
  return (x < r) ? x * (q + 1) + i : r * (q + 1) + (x - r) * q + i;
}

// ---------------- prep kernels ----------------

#define AL256(x) (((x) + 255) & ~255)

__global__ void k_sort1(const int* __restrict__ roles, int* __restrict__ ctrl) {
  __shared__ int cnt[NR];
  const int t = threadIdx.x;
  if (t < NR) cnt[t] = 0;
  __syncthreads();
  int c0 = 0, c1 = 0, c2 = 0;
  for (int i = t; i < E_TOT; i += 1024) {
    const int ro = roles[i];
    c0 += (ro == 0); c1 += (ro == 1); c2 += (ro == 2);
  }
  if (c0) atomicAdd(&cnt[0], c0);
  if (c1) atomicAdd(&cnt[1], c1);
  if (c2) atomicAdd(&cnt[2], c2);
  __syncthreads();
  if (t == 0) {
    const int off1 = AL256(cnt[0]);
    const int off2 = AL256(off1 + cnt[1]);
    const int ptot = AL256(off2 + cnt[2]);
    ctrl[0] = cnt[0]; ctrl[1] = cnt[1]; ctrl[2] = cnt[2];
    ctrl[4] = 0; ctrl[5] = off1; ctrl[6] = off2; ctrl[7] = ptot;
    ctrl[9] = 0; ctrl[10] = off1; ctrl[11] = off2;
  }
}

__global__ void k_scatter(const int* __restrict__ roles, int* __restrict__ ctrl,
                          int* __restrict__ perm) {
  int e = blockIdx.x * 256 + threadIdx.x;
  int lane = threadIdx.x & 63;
  int role = roles[e];
#pragma unroll
  for (int r = 0; r < NR; ++r) {
    unsigned long long m = __ballot(role == r);
    if (!m) continue;
    int leader = __ffsll((unsigned long long)m) - 1;
    int base = 0;
    if (lane == leader) base = atomicAdd(&ctrl[9 + r], (int)__popcll(m));
    base = __shfl(base, leader);
    if (role == r) {
      int rank = (int)__popcll(m & ((1ull << lane) - 1ull));
      perm[base + rank] = e;
    }
  }
}

// fill pad slots through EPAD_MAX so k_gather reads valid perm everywhere
__global__ void k_padfill(const int* __restrict__ ctrl, int* __restrict__ perm) {
#pragma unroll
  for (int r = 0; r < NR; ++r) {
    const int start = ctrl[4 + r] + ctrl[r];
    const int end = (r < 2) ? ctrl[5 + r] : EPAD_MAX;
    const int fill = (ctrl[r] > 0) ? perm[ctrl[4 + r]] : 0;
    for (int i = start + (int)threadIdx.x; i < end; i += 256) perm[i] = fill;
  }
}

__global__ void k_convw(const float* __restrict__ W, const float* __restrict__ U,
                        const float* __restrict__ P1, const float* __restrict__ P2,
                        const int* __restrict__ dlayer, short* __restrict__ dst) {
  const int per = NR * HD * HD;
  const int which = blockIdx.y;
  const float* src = (which == 0) ? W : (which == 1) ? U : (which == 2) ? P1 : P2;
  src += (size_t)dlayer[0] * per;
  short* d = dst + (size_t)which * per;
  int i = (blockIdx.x * 256 + threadIdx.x) * 4;
  if (i >= per) return;
  float4 v = *(const float4*)(src + i);
  short4 o;
  o.x = (short)f2bf(v.x); o.y = (short)f2bf(v.y);
  o.z = (short)f2bf(v.z); o.w = (short)f2bf(v.w);
  *(short4*)(d + i) = o;
}

// gather-by-perm + convert to bf16, sorted+padded rows (64 threads/row)
__global__ void k_gather(const float* __restrict__ v, const float* __restrict__ r,
                         const int* __restrict__ perm,
                         short* __restrict__ vbf, short* __restrict__ rbf) {
  const int idx = blockIdx.x * 256 + threadIdx.x;   // EPAD_MAX*64 threads
  const int row = idx >> 6;
  const int kc = (idx & 63) << 3;
  const int g = perm[row];
  const float4* pv = (const float4*)(v + (size_t)g * HD + kc);
  const float4* pr = (const float4*)(r + (size_t)g * HD + kc);
  const float4 a0 = pv[0], a1 = pv[1];
  const float4 b0 = pr[0], b1 = pr[1];
  short8 sa, sb;
#pragma unroll
  for (int j = 0; j < 4; ++j) {
    sa[j] = (short)f2bf(((const float*)&a0)[j]);
    sa[4 + j] = (short)f2bf(((const float*)&a1)[j]);
    sb[j] = (short)f2bf(((const float*)&b0)[j]);
    sb[4 + j] = (short)f2bf(((const float*)&b1)[j]);
  }
  *(short8*)(vbf + (size_t)row * HD + kc) = sa;
  *(short8*)(rbf + (size_t)row * HD + kc) = sb;
}

// ---------------- 4-phase pipelined GEMM (R7/R10-verified core) ----------------
// BM=BN=256, BK=64, 512 thr = 8 waves (2M x 4N), wave tile 128x64.
// LDS 128KB: [slot 0/1][A 2048 units | B 2048 units], unit = short8 (16B).
// Unit layout: half*1024 + (row&127)*8 + (u ^ (row&7))  [XOR swizzle].
// Per K-tile t: P0 B-frags+A-q0, issue A(t+1)->nxt; P1/P2 A-q1/q2, stage
// B(t+2) halves into cur (B dead after P0); P3 A-q3, write A(t+1), vmcnt(4).
// NEW (R11): LDS-staged coalesced epilogue (fixes 2.1x write amplification
// measured R10: 145MB WRITE for a 68.7MB output).
//
// AM 0: A via global_load_lds. AM 1: A = vp*rp product, reg-staged.
// OM 0: bf16 + bias. OM 1: bf16 + bias + relu. OM 2: f32 perm-scatter.
template <int AM, int OM, int PAIRED>
__global__ __launch_bounds__(512, 2) void k_gemm(
    const short* __restrict__ A0, const short* __restrict__ A1,
    const short* __restrict__ B0, const short* __restrict__ B1,
    const float* __restrict__ bias0, const float* __restrict__ bias1,
    const int* __restrict__ dlayer, const int* __restrict__ ctrl,
    const int* __restrict__ perm, short* __restrict__ outS0,
    short* __restrict__ outS1, float* __restrict__ outF) {
  __shared__ short8 lds8[2][4096];   // 128 KB

  int lb = chunk_swz<PAIRED ? NBLK2 : NBLK>(blockIdx.x);
  int pair = 0;
  if constexpr (PAIRED) { pair = lb >= NBLK ? 1 : 0; lb -= pair * NBLK; }
  const int m0 = (lb >> 1) * 256, n0 = (lb & 1) * 256;
  if (m0 >= ctrl[7]) return;
  const int role = (m0 >= ctrl[6]) ? 2 : (m0 >= ctrl[5] ? 1 : 0);

  const int tid = threadIdx.x;
  const int lane = tid & 63;
  const int wv = tid >> 6;
  const int wr = wv >> 2, wc = wv & 3;
  const int krow = lane & 15, ku = lane >> 4;

  const short* Brole = (PAIRED && pair ? B1 : B0) + (size_t)role * HD * HD;
  const short* Ap = (PAIRED && pair) ? A1 : A0;

  // B stage source offsets (elements, without k0); g = j*512+tid
  unsigned bsrc[4];
#pragma unroll
  for (int j = 0; j < 4; ++j) {
    const int g = j * 512 + tid;
    const int u = (g & 7) ^ ((g >> 3) & 7);
    bsrc[j] = (unsigned)(n0 + (g >> 3)) * HD + u * 8;
  }
  // A stage descriptors
  unsigned asrc[4];                    // AM0 gload
  unsigned aoff[4];                    // AM1 reg-stage row offsets
  if constexpr (AM == 0) {
#pragma unroll
    for (int j = 0; j < 4; ++j) {
      const int g = j * 512 + tid;
      const int u = (g & 7) ^ ((g >> 3) & 7);
      asrc[j] = (unsigned)(m0 + (g >> 3)) * HD + u * 8;
    }
  } else {
    const int uA = ((tid & 7) ^ ((tid >> 3) & 7)) * 8;
#pragma unroll
    for (int i = 0; i < 4; ++i)
      aoff[i] = (unsigned)(m0 + (tid >> 3) + i * 64) * HD + uA;
  }

  // fragment LDS indices
  int kx[2];
#pragma unroll
  for (int ks = 0; ks < 2; ++ks) kx[ks] = (ks * 4 + ku) ^ (krow & 7);
  const int gA = wr * 1024 + krow * 8;
  const int gB = 2048 + (wc >> 1) * 1024 + ((wc & 1) * 64 + krow) * 8;

  f32x4 acc[8][4];
#pragma unroll
  for (int a = 0; a < 8; ++a)
#pragma unroll
    for (int b = 0; b < 4; ++b) acc[a][b] = (f32x4)0.f;

  short8 av[4], ar[4];
  short8 fa[2][2], fb[4][2];

#define ISSUE_A(K0)                                                            \
  if constexpr (AM == 1) {                                                     \
    _Pragma("unroll") for (int i = 0; i < 4; ++i) {                            \
      av[i] = *(const short8*)(A0 + (size_t)aoff[i] + (K0));                   \
      ar[i] = *(const short8*)(A1 + (size_t)aoff[i] + (K0));                   \
    }                                                                          \
  } else {                                                                     \
    _Pragma("unroll") for (int j = 0; j < 4; ++j)                              \
      gload_lds16(Ap + (size_t)asrc[j] + (K0), Ln + j * 512 + tid);            \
  }

#define WRITE_A()                                                              \
  if constexpr (AM == 1) {                                                     \
    _Pragma("unroll") for (int i = 0; i < 4; ++i) {                            \
      short8 o;                                                                \
      _Pragma("unroll") for (int j = 0; j < 8; ++j)                            \
        o[j] = (short)f2bf(bf2f((unsigned short)av[i][j]) *                    \
                           bf2f((unsigned short)ar[i][j]));                    \
      Ln[i * 512 + tid] = o;                                                   \
    }                                                                          \
  }

#define STAGE_B(JB, K0)                                                        \
  _Pragma("unroll") for (int j = JB; j < (JB) + 2; ++j)                        \
    gload_lds16(Brole + (size_t)bsrc[j] + (K0), Lc + 2048 + j * 512 + tid);

#define READ_FA(MI0)                                                           \
  _Pragma("unroll") for (int mi = 0; mi < 2; ++mi)                             \
    _Pragma("unroll") for (int ks = 0; ks < 2; ++ks)                           \
      fa[mi][ks] = Lc[gA + ((MI0) + mi) * 128 + kx[ks]];

#define PHASE_TAIL(MI0)                                                        \
  __builtin_amdgcn_s_barrier();                                                \
  asm volatile("s_waitcnt lgkmcnt(0)" ::: "memory");                           \
  __builtin_amdgcn_sched_barrier(0);                                           \
  __builtin_amdgcn_s_setprio(1);                                               \
  _Pragma("unroll") for (int ks = 0; ks < 2; ++ks)                             \
    _Pragma("unroll") for (int mi = 0; mi < 2; ++mi)                           \
      _Pragma("unroll") for (int ni = 0; ni < 4; ++ni)                         \
        acc[(MI0) + mi][ni] = __builtin_amdgcn_mfma_f32_16x16x32_bf16(         \
            fa[mi][ks], fb[ni][ks], acc[(MI0) + mi][ni], 0, 0, 0);             \
  __builtin_amdgcn_s_setprio(0);                                               \
  __builtin_amdgcn_s_barrier();

  // ---- prologue: A(0), B(0) -> slot0, B(1) -> slot1 ----
  {
    short8* Ln = &lds8[0][0];
    short8* Lc = &lds8[0][0];
    ISSUE_A(0)
    STAGE_B(0, 0) STAGE_B(2, 0)
    Lc = &lds8[1][0];
    STAGE_B(0, 64) STAGE_B(2, 64)
    asm volatile("s_waitcnt vmcnt(4)" ::: "memory");
    WRITE_A()
    asm volatile("s_waitcnt lgkmcnt(0)" ::: "memory");
    __builtin_amdgcn_s_barrier();
  }

  int cur = 0;
  for (int t = 0; t < 8; ++t) {
    short8* Lc = &lds8[cur][0];
    short8* Ln = &lds8[cur ^ 1][0];
    const int k0a = (t + 1) * 64;
    const int k0b = (t + 2) * 64;

    // P0: B-frags + A q0; issue next A
#pragma unroll
    for (int ni = 0; ni < 4; ++ni)
#pragma unroll
      for (int ks = 0; ks < 2; ++ks)
        fb[ni][ks] = Lc[gB + ni * 128 + kx[ks]];
    READ_FA(0)
    if (t < 7) { ISSUE_A(k0a) }
    PHASE_TAIL(0)

    // P1: A q1; stage B_lo(t+2) into cur
    READ_FA(2)
    if (t < 6) { STAGE_B(0, k0b) }
    PHASE_TAIL(2)

    // P2: A q2; stage B_hi(t+2) into cur
    READ_FA(4)
    if (t < 6) { STAGE_B(2, k0b) }
    PHASE_TAIL(4)

    // P3: A q3; write A(t+1) -> cur^1; counted vmcnt
    READ_FA(6)
    if (t < 7) { WRITE_A() }
    if (t < 6) asm volatile("s_waitcnt vmcnt(4)" ::: "memory");
    else       asm volatile("s_waitcnt vmcnt(0)" ::: "memory");
    PHASE_TAIL(6)

    cur ^= 1;
  }

  // ---- epilogue: LDS-staged, full-line coalesced stores ----
  const int ld = dlayer[0];
  const float* bias = (PAIRED && pair ? bias1 : bias0) +
                      ((size_t)ld * NR + role) * HD + n0;
  short* outS = (PAIRED && pair) ? outS1 : outS0;

  if constexpr (OM != 2) {
    // bf16: two half-tiles of 128 rows; LDS tile [128][260] shorts (66,560 B).
    short* LE = (short*)&lds8[0][0];
#pragma unroll
    for (int half = 0; half < 2; ++half) {
      __syncthreads();                 // prev phase/reads done, LDS free
      if (wr == half) {
#pragma unroll
        for (int ni = 0; ni < 4; ++ni) {
          const int col = wc * 64 + ni * 16 + krow;
          const float b = bias[col];
#pragma unroll
          for (int mi = 0; mi < 8; ++mi) {
#pragma unroll
            for (int j = 0; j < 4; ++j) {
              float val = acc[mi][ni][j] + b;
              if constexpr (OM == 1) val = fmaxf(val, 0.f);
              LE[(mi * 16 + ku * 4 + j) * 260 + col] = (short)f2bf(val);
            }
          }
        }
      }
      __syncthreads();
#pragma unroll
      for (int it2 = 0; it2 < 8; ++it2) {
        const int row = it2 * 16 + (tid >> 5);
        const int u = tid & 31;
        short8 val = *(short8*)&LE[row * 260 + u * 8];
        *(short8*)&outS[(size_t)(m0 + half * 128 + row) * HD + n0 + u * 8] = val;
      }
    }
  } else {
    // f32 perm-scatter: four quarter-tiles of 64 rows; LDS [64][260] floats.
    float* LF = (float*)&lds8[0][0];
#pragma unroll
    for (int q = 0; q < 4; ++q) {
      __syncthreads();
      if (wr == (q >> 1)) {
        const int mibase = (q & 1) * 4;
#pragma unroll
        for (int ni = 0; ni < 4; ++ni) {
          const int col = wc * 64 + ni * 16 + krow;
          const float b = bias[col];
#pragma unroll
          for (int mi = 0; mi < 4; ++mi) {
#pragma unroll
            for (int j = 0; j < 4; ++j)
              LF[(mi * 16 + ku * 4 + j) * 260 + col] =
                  acc[mibase + mi][ni][j] + b;
          }
        }
      }
      __syncthreads();
#pragma unroll
      for (int it2 = 0; it2 < 8; ++it2) {
        const int row = it2 * 8 + (tid >> 6);
        const int u = tid & 63;
        f32x4 val = *(f32x4*)&LF[row * 260 + u * 4];
        const int gr = m0 + q * 64 + row;
        *(f32x4*)&outF[(size_t)perm[gr] * HD + n0 + u * 4] = val;
      }
    }
  }
#undef ISSUE_A
#undef WRITE_A
#undef STAGE_B
#undef READ_FA
#undef PHASE_TAIL
}

// ---------------- launch ----------------

extern "C" void kernel_launch(void* const* d_in, const int* in_sizes, int n_in,
                              void* d_out, int out_size, void* d_ws, size_t ws_size,
                              hipStream_t stream) {
  const float* v    = (const float*)d_in[0];
  const float* r    = (const float*)d_in[1];
  const int*   rol  = (const int*)d_in[2];
  const float* W    = (const float*)d_in[3];
  const float* Wb   = (const float*)d_in[4];
  const float* U    = (const float*)d_in[5];
  const float* Ub   = (const float*)d_in[6];
  const float* P1   = (const float*)d_in[7];
  const float* P1b  = (const float*)d_in[8];
  const float* P2   = (const float*)d_in[9];
  const float* P2b  = (const float*)d_in[10];
  const int*   dly  = (const int*)d_in[11];

  char* ws = (char*)d_ws;
  int* ctrl = (int*)ws;                          // 256 B
  int* perm = (int*)(ws + 256);                  // EPAD_MAX ints -> ends 134,400
  short* Wbf = (short*)(ws + 134400);            // 4 x NR*HD*HD bf16
  short* Ubf  = Wbf + (size_t)NR * HD * HD;
  short* P1bf = Ubf + (size_t)NR * HD * HD;
  short* P2bf = P1bf + (size_t)NR * HD * HD;     // ends 6,425,856
  short* vbf = (short*)(ws + 6425856);           // EPAD_MAX*HD bf16 -> ends 40,766,720
  short* rbf = vbf + (size_t)EPAD_MAX * HD;      // ends 75,107,584 (proven bound)
  short* vp  = (short*)d_out;                    // d_out front 34.3MB (dead before S3)
  float* out = (float*)d_out;

  const bool bigws = ws_size >= 109448448ull;    // rp extension fits?
  short* rp = bigws ? (short*)(ws + 75107584) : vbf;  // paired: ws ext; seq: over vbf
  short* tb = rbf;                               // over rbf (dead after S1 reads it)

  k_sort1<<<1, 1024, 0, stream>>>(rol, ctrl);
  k_scatter<<<E_TOT / 256, 256, 0, stream>>>(rol, ctrl, perm);
  k_padfill<<<1, 256, 0, stream>>>(ctrl, perm);
  k_convw<<<dim3((NR * HD * HD) / 4 / 256, 4, 1), 256, 0, stream>>>(W, U, P1, P2, dly, Wbf);
  k_gather<<<EPAD_MAX * 64 / 256, 256, 0, stream>>>(v, r, perm, vbf, rbf);

  if (bigws) {
    // S1 paired: vp = vbf@W^T+wb, rp = rbf@U^T+ub  (one 524-block dispatch)
    k_gemm<0, 0, 1><<<NBLK2, 512, 0, stream>>>(vbf, rbf, Wbf, Ubf, Wb, Ub,
                                               dly, ctrl, perm, vp, rp, nullptr);
  } else {
    k_gemm<0, 0, 0><<<NBLK, 512, 0, stream>>>(vbf, nullptr, Wbf, nullptr, Wb, nullptr,
                                              dly, ctrl, perm, vp, nullptr, nullptr);
    k_gemm<0, 0, 0><<<NBLK, 512, 0, stream>>>(rbf, nullptr, Ubf, nullptr, Ub, nullptr,
                                              dly, ctrl, perm, rp, nullptr, nullptr);
  }
  // S2: tb = relu((vp*rp)@P1^T + b1)  (product reg-staged; tb -> over rbf)
  k_gemm<1, 1, 0><<<NBLK, 512, 0, stream>>>(vp, rp, P1bf, nullptr, P1b, nullptr,
                                            dly, ctrl, perm, tb, nullptr, nullptr);
  // S3: out[perm] = tb@P2^T + b2      (overwrites all of d_out)
  k_gemm<0, 2, 0><<<NBLK, 512, 0, stream>>>(tb, nullptr, P2bf, nullptr, P2b, nullptr,
                                            dly, ctrl, perm, nullptr, nullptr, out);

  (void)in_sizes; (void)n_in; (void)out_size;
}

// Round 12
// 222.492 us; speedup vs baseline: 4.7359x; 1.0886x over previous
//
#include <hip/hip_runtime.h>
#include <cstdint>
#include <cstddef>

#define E_TOT 32768
#define HD    512
#define NR    3
#define EPAD_MAX 33152          // E_TOT + 3*128
#define NTM   259               // EPAD_MAX / 128
#define NB    1036              // NTM * 4 N-tiles (BN=128)
#define NB2   2072              // paired S1

typedef __attribute__((ext_vector_type(8))) short short8;
typedef __attribute__((ext_vector_type(4))) float f32x4;

static __device__ __forceinline__ unsigned short f2bf(float f) {
  union { float f; unsigned int u; } x; x.f = f;
  unsigned int u = x.u;
  return (unsigned short)((u + 0x7fffu + ((u >> 16) & 1u)) >> 16);  // RNE
}
static __device__ __forceinline__ float bf2f(unsigned short h) {
  union { unsigned int u; float f; } x; x.u = ((unsigned int)h) << 16;
  return x.f;
}

static __device__ __forceinline__ void gload_lds16(const void* g, void* l) {
  __builtin_amdgcn_global_load_lds(
      (const __attribute__((address_space(1))) unsigned int*)g,
      (__attribute__((address_space(3))) unsigned int*)l, 16, 0, 0);
}

// bijective chunked XCD swizzle (m204)
template <int NWG>
static __device__ __forceinline__ int chunk_swz(int bid) {
  constexpr int q = NWG / 8, r = NWG % 8;
  const int x = bid & 7, i = bid >> 3;
  return (x < r) ? x * (q + 1) + i : r * (q + 1) + (x - r) * q + i;
}

// ---------------- prep kernels ----------------

#define AL128(x) (((x) + 127) & ~127)

__global__ void k_sort1(const int* __restrict__ roles, int* __restrict__ ctrl) {
  __shared__ int cnt[NR];
  const int t = threadIdx.x;
  if (t < NR) cnt[t] = 0;
  __syncthreads();
  int c0 = 0, c1 = 0, c2 = 0;
  for (int i = t; i < E_TOT; i += 1024) {
    const int ro = roles[i];
    c0 += (ro == 0); c1 += (ro == 1); c2 += (ro == 2);
  }
  if (c0) atomicAdd(&cnt[0], c0);
  if (c1) atomicAdd(&cnt[1], c1);
  if (c2) atomicAdd(&cnt[2], c2);
  __syncthreads();
  if (t == 0) {
    const int off1 = AL128(cnt[0]);
    const int off2 = AL128(off1 + cnt[1]);
    const int ptot = AL128(off2 + cnt[2]);
    ctrl[0] = cnt[0]; ctrl[1] = cnt[1]; ctrl[2] = cnt[2];
    ctrl[4] = 0; ctrl[5] = off1; ctrl[6] = off2; ctrl[7] = ptot;
    ctrl[9] = 0; ctrl[10] = off1; ctrl[11] = off2;
  }
}

__global__ void k_scatter(const int* __restrict__ roles, int* __restrict__ ctrl,
                          int* __restrict__ perm) {
  int e = blockIdx.x * 256 + threadIdx.x;
  int lane = threadIdx.x & 63;
  int role = roles[e];
#pragma unroll
  for (int r = 0; r < NR; ++r) {
    unsigned long long m = __ballot(role == r);
    if (!m) continue;
    int leader = __ffsll((unsigned long long)m) - 1;
    int base = 0;
    if (lane == leader) base = atomicAdd(&ctrl[9 + r], (int)__popcll(m));
    base = __shfl(base, leader);
    if (role == r) {
      int rank = (int)__popcll(m & ((1ull << lane) - 1ull));
      perm[base + rank] = e;
    }
  }
}

// fill pad slots through EPAD_MAX so k_gather reads valid perm everywhere
__global__ void k_padfill(const int* __restrict__ ctrl, int* __restrict__ perm) {
#pragma unroll
  for (int r = 0; r < NR; ++r) {
    const int start = ctrl[4 + r] + ctrl[r];
    const int end = (r < 2) ? ctrl[5 + r] : EPAD_MAX;
    const int fill = (ctrl[r] > 0) ? perm[ctrl[4 + r]] : 0;
    for (int i = start + (int)threadIdx.x; i < end; i += 256) perm[i] = fill;
  }
}

__global__ void k_convw(const float* __restrict__ W, const float* __restrict__ U,
                        const float* __restrict__ P1, const float* __restrict__ P2,
                        const int* __restrict__ dlayer, short* __restrict__ dst) {
  const int per = NR * HD * HD;
  const int which = blockIdx.y;
  const float* src = (which == 0) ? W : (which == 1) ? U : (which == 2) ? P1 : P2;
  src += (size_t)dlayer[0] * per;
  short* d = dst + (size_t)which * per;
  int i = (blockIdx.x * 256 + threadIdx.x) * 4;
  if (i >= per) return;
  float4 v = *(const float4*)(src + i);
  short4 o;
  o.x = (short)f2bf(v.x); o.y = (short)f2bf(v.y);
  o.z = (short)f2bf(v.z); o.w = (short)f2bf(v.w);
  *(short4*)(d + i) = o;
}

// gather-by-perm + convert to bf16, sorted+padded rows (64 threads/row)
__global__ void k_gather(const float* __restrict__ v, const float* __restrict__ r,
                         const int* __restrict__ perm,
                         short* __restrict__ vbf, short* __restrict__ rbf) {
  const int idx = blockIdx.x * 256 + threadIdx.x;   // EPAD_MAX*64 threads
  const int row = idx >> 6;
  const int kc = (idx & 63) << 3;
  const int g = perm[row];
  const float4* pv = (const float4*)(v + (size_t)g * HD + kc);
  const float4* pr = (const float4*)(r + (size_t)g * HD + kc);
  const float4 a0 = pv[0], a1 = pv[1];
  const float4 b0 = pr[0], b1 = pr[1];
  short8 sa, sb;
#pragma unroll
  for (int j = 0; j < 4; ++j) {
    sa[j] = (short)f2bf(((const float*)&a0)[j]);
    sa[4 + j] = (short)f2bf(((const float*)&a1)[j]);
    sb[j] = (short)f2bf(((const float*)&b0)[j]);
    sb[4 + j] = (short)f2bf(((const float*)&b1)[j]);
  }
  *(short8*)(vbf + (size_t)row * HD + kc) = sa;
  *(short8*)(rbf + (size_t)row * HD + kc) = sb;
}

// ---------------- m97-style GEMM ----------------
// BM=BN=128, BK=64. 256 thr = 4 waves (2M x 2N), wave tile 64x64.
// acc[4][4] f32x4 = 64 floats. LDS: As/Bs [128][64] shorts (32KB, SINGLE
// buffer) + EP 17.4KB epilogue staging -> ~50KB, ~3 blocks/CU (m97's
// occupancy mechanism: cross-block overlap hides the barrier drain, m114).
// Plain __syncthreads loop — no hand-rolled barriers (m97: 874 TF measured).
// XOR swizzle: LDS[row][us] holds data-unit us^(row&7); sources pre-swizzled,
// reads XOR'd (R5-verified 0-conflict). D-frag: col=lane&15, row=(lane>>4)*4+reg.
//
// AM 0: A via global_load_lds. AM 1: A = A0*A1 product, reg-staged (T14).
// OM 0: bf16 + bias. OM 1: bf16 + bias + relu. OM 2: f32 perm-scatter.
// All epilogues LDS-staged for full-line stores (R11-verified write-ideal).
template <int AM, int OM, int PAIRED>
__global__ __launch_bounds__(256) void k_mm(
    const short* __restrict__ A0, const short* __restrict__ A1,
    const short* __restrict__ B0, const short* __restrict__ B1,
    const float* __restrict__ bias0, const float* __restrict__ bias1,
    const int* __restrict__ dlayer, const int* __restrict__ ctrl,
    const int* __restrict__ perm, short* __restrict__ outS0,
    short* __restrict__ outS1, float* __restrict__ outF) {
  __shared__ short As[128 * 64];
  __shared__ short Bs[128 * 64];
  __shared__ short EP[64 * 136];   // bf16 halves [64][136] / f32 quarters [32][132]

  int lb = chunk_swz<PAIRED ? NB2 : NB>(blockIdx.x);
  int pair = 0;
  if constexpr (PAIRED) { pair = lb >= NB ? 1 : 0; lb -= pair * NB; }
  const int m0 = (lb >> 2) * 128, n0 = (lb & 3) * 128;
  if (m0 >= ctrl[7]) return;
  const int role = (m0 >= ctrl[6]) ? 2 : (m0 >= ctrl[5] ? 1 : 0);

  const int tid = threadIdx.x;
  const int lane = tid & 63;
  const int wv = tid >> 6;
  const int wr = wv >> 1, wc = wv & 1;
  const int krow = lane & 15, ku = lane >> 4;

  const short* Brole = (PAIRED && pair ? B1 : B0) + (size_t)role * HD * HD;
  const short* Ap = (PAIRED && pair) ? A1 : A0;

  // staging: g = j*256+tid; row=g>>3; storage-unit us=g&7 holds data-unit
  // ud = us ^ (row&7); source pre-swizzled accordingly.
  unsigned asrc[4], bsrc[4];
#pragma unroll
  for (int j = 0; j < 4; ++j) {
    const int g = j * 256 + tid;
    const int row = g >> 3;
    const int ud = (g & 7) ^ (row & 7);
    asrc[j] = (unsigned)(m0 + row) * HD + ud * 8;
    bsrc[j] = (unsigned)(n0 + row) * HD + ud * 8;
  }

  f32x4 acc[4][4];
#pragma unroll
  for (int a = 0; a < 4; ++a)
#pragma unroll
    for (int b = 0; b < 4; ++b) acc[a][b] = (f32x4)0.f;

  for (int t = 0; t < 8; ++t) {
    const int k0 = t * 64;
    // ---- stage ----
#pragma unroll
    for (int j = 0; j < 4; ++j)
      gload_lds16(Brole + (size_t)bsrc[j] + k0, &Bs[(j * 256 + tid) * 8]);
    if constexpr (AM == 0) {
#pragma unroll
      for (int j = 0; j < 4; ++j)
        gload_lds16(Ap + (size_t)asrc[j] + k0, &As[(j * 256 + tid) * 8]);
    } else {
#pragma unroll
      for (int j = 0; j < 4; ++j) {
        const short8 av = *(const short8*)(A0 + (size_t)asrc[j] + k0);
        const short8 ar = *(const short8*)(A1 + (size_t)asrc[j] + k0);
        short8 o;
#pragma unroll
        for (int e = 0; e < 8; ++e)
          o[e] = (short)f2bf(bf2f((unsigned short)av[e]) *
                             bf2f((unsigned short)ar[e]));
        *(short8*)&As[(j * 256 + tid) * 8] = o;
      }
    }
    __syncthreads();   // drains gload_lds + ds_write
    // ---- compute ----
    short8 fa[4][2], fb[4][2];
#pragma unroll
    for (int mi = 0; mi < 4; ++mi)
#pragma unroll
      for (int ks = 0; ks < 2; ++ks) {
        const int row = wr * 64 + mi * 16 + krow;
        fa[mi][ks] = *(const short8*)&As[row * 64 + (((ks * 4 + ku) ^ (row & 7)) * 8)];
      }
#pragma unroll
    for (int ni = 0; ni < 4; ++ni)
#pragma unroll
      for (int ks = 0; ks < 2; ++ks) {
        const int row = wc * 64 + ni * 16 + krow;
        fb[ni][ks] = *(const short8*)&Bs[row * 64 + (((ks * 4 + ku) ^ (row & 7)) * 8)];
      }
#pragma unroll
    for (int ks = 0; ks < 2; ++ks)
#pragma unroll
      for (int mi = 0; mi < 4; ++mi)
#pragma unroll
        for (int ni = 0; ni < 4; ++ni)
          acc[mi][ni] = __builtin_amdgcn_mfma_f32_16x16x32_bf16(
              fa[mi][ks], fb[ni][ks], acc[mi][ni], 0, 0, 0);
    __syncthreads();   // LDS reads done before next stage
  }

  // ---- epilogue: LDS-staged, full-line coalesced ----
  const int ld = dlayer[0];
  const float* bias = (PAIRED && pair ? bias1 : bias0) +
                      ((size_t)ld * NR + role) * HD + n0;
  short* outS = (PAIRED && pair) ? outS1 : outS0;

  if constexpr (OM != 2) {
    // two half-tiles of 64 rows; EP as [64][136] shorts (272B rows, 16B-aligned)
#pragma unroll
    for (int half = 0; half < 2; ++half) {
      __syncthreads();
      if (wr == half) {
#pragma unroll
        for (int ni = 0; ni < 4; ++ni) {
          const int col = wc * 64 + ni * 16 + krow;
          const float b = bias[col];
#pragma unroll
          for (int mi = 0; mi < 4; ++mi)
#pragma unroll
            for (int j = 0; j < 4; ++j) {
              float val = acc[mi][ni][j] + b;
              if constexpr (OM == 1) val = fmaxf(val, 0.f);
              EP[(mi * 16 + ku * 4 + j) * 136 + col] = (short)f2bf(val);
            }
        }
      }
      __syncthreads();
#pragma unroll
      for (int i = 0; i < 4; ++i) {
        const int g = i * 256 + tid;
        const int row = g >> 4, u = g & 15;
        short8 vv = *(const short8*)&EP[row * 136 + u * 8];
        *(short8*)&outS[(size_t)(m0 + half * 64 + row) * HD + n0 + u * 8] = vv;
      }
    }
  } else {
    // four quarter-tiles of 32 rows; EP as [32][132] floats (528B rows)
    float* LF = (float*)EP;
#pragma unroll
    for (int q = 0; q < 4; ++q) {
      __syncthreads();
      if (wr == (q >> 1)) {
#pragma unroll
        for (int ni = 0; ni < 4; ++ni) {
          const int col = wc * 64 + ni * 16 + krow;
          const float b = bias[col];
#pragma unroll
          for (int mi2 = 0; mi2 < 2; ++mi2) {
            const int mi = (q & 1) * 2 + mi2;
#pragma unroll
            for (int j = 0; j < 4; ++j)
              LF[(mi2 * 16 + ku * 4 + j) * 132 + col] = acc[mi][ni][j] + b;
          }
        }
      }
      __syncthreads();
#pragma unroll
      for (int i = 0; i < 4; ++i) {
        const int g = i * 256 + tid;
        const int row = g >> 5, u = g & 31;
        f32x4 vv = *(const f32x4*)&LF[row * 132 + u * 4];
        *(f32x4*)&outF[(size_t)perm[m0 + q * 32 + row] * HD + n0 + u * 4] = vv;
      }
    }
  }
}

// ---------------- launch ----------------

extern "C" void kernel_launch(void* const* d_in, const int* in_sizes, int n_in,
                              void* d_out, int out_size, void* d_ws, size_t ws_size,
                              hipStream_t stream) {
  const float* v    = (const float*)d_in[0];
  const float* r    = (const float*)d_in[1];
  const int*   rol  = (const int*)d_in[2];
  const float* W    = (const float*)d_in[3];
  const float* Wb   = (const float*)d_in[4];
  const float* U    = (const float*)d_in[5];
  const float* Ub   = (const float*)d_in[6];
  const float* P1   = (const float*)d_in[7];
  const float* P1b  = (const float*)d_in[8];
  const float* P2   = (const float*)d_in[9];
  const float* P2b  = (const float*)d_in[10];
  const int*   dly  = (const int*)d_in[11];

  char* ws = (char*)d_ws;
  int* ctrl = (int*)ws;                          // 256 B
  int* perm = (int*)(ws + 256);                  // EPAD_MAX ints -> ends 132,864
  short* Wbf = (short*)(ws + 132864);            // 4 x NR*HD*HD bf16
  short* Ubf  = Wbf + (size_t)NR * HD * HD;
  short* P1bf = Ubf + (size_t)NR * HD * HD;
  short* P2bf = P1bf + (size_t)NR * HD * HD;     // ends 6,424,320
  short* vbf = (short*)(ws + 6424320);           // EPAD_MAX*HD bf16 -> ends 40,371,968
  short* rbf = vbf + (size_t)EPAD_MAX * HD;      // ends 74,319,616
  short* vp  = (short*)d_out;                    // d_out front (dead before S3 writes)
  float* out = (float*)d_out;

  const bool bigws = ws_size >= 108267264ull;
  short* rp = bigws ? (short*)(ws + 74319616) : vbf;  // paired: ws ext; seq: over vbf
  short* tb = rbf;                               // over rbf (dead after S1)

  k_sort1<<<1, 1024, 0, stream>>>(rol, ctrl);
  k_scatter<<<E_TOT / 256, 256, 0, stream>>>(rol, ctrl, perm);
  k_padfill<<<1, 256, 0, stream>>>(ctrl, perm);
  k_convw<<<dim3((NR * HD * HD) / 4 / 256, 4, 1), 256, 0, stream>>>(W, U, P1, P2, dly, Wbf);
  k_gather<<<EPAD_MAX * 64 / 256, 256, 0, stream>>>(v, r, perm, vbf, rbf);

  if (bigws) {
    // S1 paired: vp = vbf@W^T+wb, rp = rbf@U^T+ub (one 2072-block dispatch)
    k_mm<0, 0, 1><<<NB2, 256, 0, stream>>>(vbf, rbf, Wbf, Ubf, Wb, Ub,
                                           dly, ctrl, perm, vp, rp, nullptr);
  } else {
    k_mm<0, 0, 0><<<NB, 256, 0, stream>>>(vbf, nullptr, Wbf, nullptr, Wb, nullptr,
                                          dly, ctrl, perm, vp, nullptr, nullptr);
    k_mm<0, 0, 0><<<NB, 256, 0, stream>>>(rbf, nullptr, Ubf, nullptr, Ub, nullptr,
                                          dly, ctrl, perm, rp, nullptr, nullptr);
  }
  // S2: tb = relu((vp*rp)@P1^T + b1)   (product reg-staged)
  k_mm<1, 1, 0><<<NB, 256, 0, stream>>>(vp, rp, P1bf, nullptr, P1b, nullptr,
                                        dly, ctrl, perm, tb, nullptr, nullptr);
  // S3: out[perm] = tb@P2^T + b2       (f32 scatter; overwrites all of d_out)
  k_mm<0, 2, 0><<<NB, 256, 0, stream>>>(tb, nullptr, P2bf, nullptr, P2b, nullptr,
                                        dly, ctrl, perm, nullptr, nullptr, out);

  (void)in_sizes; (void)n_in; (void)out_size;
}